// Round 1
// 299.834 us; speedup vs baseline: 3.2490x; 3.2490x over previous
//
#include <hip/hip_runtime.h>
#include <math.h>

// B=64, G=2048, S=64, C=3 -> 131072 groups.
// Thread-per-group rewrite: per-group arithmetic and op order are IDENTICAL to
// the previous wave-per-group kernel (bit-faithful LAPACK ssyevd emulation),
// but executed by one thread each -> no 64x wave-uniform redundancy, and the
// n=3 eigen solver lives entirely in named registers (no scratch arrays).

__device__ __forceinline__ float slapy2_(float x, float y) {
    _Pragma("clang fp contract(off)")
    float xa = fabsf(x), ya = fabsf(y);
    float w = fmaxf(xa, ya), z = fminf(xa, ya);
    if (z == 0.0f) return w;
    float t = z / w;
    return w * sqrtf(1.0f + t * t);
}

// LAPACK >= 3.10 slartg (fast path; magnitudes mid-range).
__device__ __forceinline__ void slartg_(float f, float g,
                                        float &c, float &s, float &r) {
    _Pragma("clang fp contract(off)")
    if (g == 0.0f) { c = 1.0f; s = 0.0f; r = f; return; }
    if (f == 0.0f) { c = 0.0f; s = (g >= 0.0f) ? 1.0f : -1.0f; r = fabsf(g); return; }
    float d = sqrtf(f * f + g * g);
    float p = 1.0f / d;
    c = fabsf(f) * p;
    s = g * ((f >= 0.0f) ? p : -p);
    r = (f >= 0.0f) ? d : -d;
}

__device__ __forceinline__ void slaev2_(float a, float b, float cc,
                                        float &rt1, float &rt2,
                                        float &cs1, float &sn1) {
    _Pragma("clang fp contract(off)")
    float sm = a + cc, df = a - cc;
    float adf = fabsf(df);
    float tb = b + b;
    float ab = fabsf(tb);
    float acmx, acmn;
    if (fabsf(a) > fabsf(cc)) { acmx = a; acmn = cc; } else { acmx = cc; acmn = a; }
    float rt;
    if (adf > ab)      { float t = ab / adf; rt = adf * sqrtf(1.0f + t * t); }
    else if (adf < ab) { float t = adf / ab; rt = ab * sqrtf(1.0f + t * t); }
    else                rt = ab * sqrtf(2.0f);
    int sgn1;
    if (sm < 0.0f)      { rt1 = 0.5f * (sm - rt); sgn1 = -1; rt2 = (acmx / rt1) * acmn - (b / rt1) * b; }
    else if (sm > 0.0f) { rt1 = 0.5f * (sm + rt); sgn1 =  1; rt2 = (acmx / rt1) * acmn - (b / rt1) * b; }
    else                { rt1 = 0.5f * rt; rt2 = -0.5f * rt; sgn1 = 1; }
    int sgn2;
    float cs;
    if (df >= 0.0f) { cs = df + rt; sgn2 = 1; } else { cs = df - rt; sgn2 = -1; }
    float acs = fabsf(cs);
    if (acs > ab) {
        float ct = -tb / cs;
        sn1 = 1.0f / sqrtf(1.0f + ct * ct);
        cs1 = ct * sn1;
    } else {
        if (ab == 0.0f) { cs1 = 1.0f; sn1 = 0.0f; }
        else {
            float tn = -cs / tb;
            cs1 = 1.0f / sqrtf(1.0f + tn * tn);
            sn1 = tn * cs1;
        }
    }
    if (sgn1 == sgn2) { float tn = cs1; cs1 = -sn1; sn1 = tn; }
}

// --- register-resident accessors for 1-based d[1..3], e[1..2] (cndmask, no scratch) ---
__device__ __forceinline__ float getd3(int i, float d1, float d2, float d3) {
    return (i == 1) ? d1 : ((i == 2) ? d2 : d3);
}
__device__ __forceinline__ void setd3(int i, float v, float &d1, float &d2, float &d3) {
    d1 = (i == 1) ? v : d1;
    d2 = (i == 2) ? v : d2;
    d3 = (i == 3) ? v : d3;
}
__device__ __forceinline__ float gete2(int i, float e1, float e2) {
    return (i == 1) ? e1 : e2;
}
__device__ __forceinline__ void sete2(int i, float v, float &e1, float &e2) {
    e1 = (i == 1) ? v : e1;
    e2 = (i == 2) ? v : e2;
}

// slasr single rotation on columns (j, j+1), j in {1,2}; exact reference formula.
__device__ __forceinline__ void zrot3r(int j, float ctemp, float stemp,
                                       float &z11, float &z12, float &z13,
                                       float &z21, float &z22, float &z23,
                                       float &z31, float &z32, float &z33) {
    _Pragma("clang fp contract(off)")
    if (j == 1) {
        { float t = z12; z12 = (ctemp * t) - (stemp * z11); z11 = (stemp * t) + (ctemp * z11); }
        { float t = z22; z22 = (ctemp * t) - (stemp * z21); z21 = (stemp * t) + (ctemp * z21); }
        { float t = z32; z32 = (ctemp * t) - (stemp * z31); z31 = (stemp * t) + (ctemp * z31); }
    } else {
        { float t = z13; z13 = (ctemp * t) - (stemp * z12); z12 = (stemp * t) + (ctemp * z12); }
        { float t = z23; z23 = (ctemp * t) - (stemp * z22); z22 = (stemp * t) + (ctemp * z22); }
        { float t = z33; z33 = (ctemp * t) - (stemp * z32); z32 = (stemp * t) + (ctemp * z32); }
    }
}

// ssteqr('I') n=3, faithful LAPACK control flow, all state in registers.
__device__ __forceinline__ void ssteqr3_reg(
        float &d1_, float &d2_, float &d3_, float &e1_, float &e2_,
        float &z11, float &z12, float &z13,
        float &z21, float &z22, float &z23,
        float &z31, float &z32, float &z33) {
    _Pragma("clang fp contract(off)")
    const float EPS    = 5.9604644775390625e-8f;   // slamch('E') = 2^-24
    const float EPS2   = EPS * EPS;
    const float SAFMIN = 1.17549435e-38f;
    const int n = 3, nmaxit = 3 * 30;
    int jtot = 0, l1 = 1;

#define GD(i)      getd3((i), d1_, d2_, d3_)
#define SD(i, v)   setd3((i), (v), d1_, d2_, d3_)
#define GE(i)      gete2((i), e1_, e2_)
#define SE(i, v)   sete2((i), (v), e1_, e2_)
#define ZR(j, c, s) zrot3r((j), (c), (s), z11, z12, z13, z21, z22, z23, z31, z32, z33)

    while (true) {                       // label 10
        if (l1 > n) break;
        if (l1 > 1) SE(l1 - 1, 0.0f);
        int m = n;
        for (int mm = l1; mm <= n - 1; ++mm) {
            float tst = fabsf(GE(mm));
            if (tst == 0.0f) { m = mm; break; }
            if (tst <= (sqrtf(fabsf(GD(mm))) * sqrtf(fabsf(GD(mm + 1)))) * EPS) {
                SE(mm, 0.0f); m = mm; break;
            }
        }
        int l = l1, lsv = l, lend = m, lendsv = lend;
        l1 = m + 1;
        if (lend == l) continue;
        // slascl scaling skipped: block norms ~1e2..1e4, inside [ssfmin, ssfmax]
        if (fabsf(GD(lend)) < fabsf(GD(l))) { lend = lsv; l = lendsv; }

        if (lend > l) {
            // ---- QL ----
            while (true) {               // label 40
                m = lend;
                if (l != lend) {
                    for (int mm = l; mm <= lend - 1; ++mm) {
                        float em = GE(mm);
                        float tst = em * em;
                        if (tst <= (EPS2 * fabsf(GD(mm))) * fabsf(GD(mm + 1)) + SAFMIN) { m = mm; break; }
                    }
                }
                if (m < lend) SE(m, 0.0f);
                float p = GD(l);
                if (m == l) {            // label 80
                    SD(l, p); ++l;
                    if (l <= lend) continue;
                    break;
                }
                if (m == l + 1) {
                    float rt1, rt2, c, s;
                    slaev2_(GD(l), GE(l), GD(l + 1), rt1, rt2, c, s);
                    ZR(l, c, s);
                    SD(l, rt1); SD(l + 1, rt2); SE(l, 0.0f);
                    l += 2;
                    if (l <= lend) continue;
                    break;
                }
                if (jtot == nmaxit) break;
                ++jtot;
                {
                    float el = GE(l);
                    float g = (GD(l + 1) - p) / (2.0f * el);
                    float r = slapy2_(g, 1.0f);
                    g = GD(m) - p + el / (g + ((g >= 0.0f) ? r : -r));  // sign(r,g)
                    float s = 1.0f, c = 1.0f;
                    p = 0.0f;
                    for (int i = m - 1; i >= l; --i) {
                        float ei = GE(i);
                        float f = s * ei;
                        float b = c * ei;
                        slartg_(g, f, c, s, r);
                        if (i != m - 1) SE(i + 1, r);
                        g = GD(i + 1) - p;
                        float r2 = ((GD(i) - g) * s) + ((2.0f * c) * b);
                        p = s * r2;
                        SD(i + 1, g + p);
                        g = (c * r2) - b;
                        ZR(i, c, -s);    // QL stores -s
                    }
                    SD(l, GD(l) - p);
                    SE(l, g);
                }
            }
        } else if (lend < l) {
            // ---- QR ----
            while (true) {               // label 90
                m = lend;
                if (l != lend) {
                    for (int mm = l; mm >= lend + 1; --mm) {
                        float em = GE(mm - 1);
                        float tst = em * em;
                        if (tst <= (EPS2 * fabsf(GD(mm))) * fabsf(GD(mm - 1)) + SAFMIN) { m = mm; break; }
                    }
                }
                if (m > lend) SE(m - 1, 0.0f);
                float p = GD(l);
                if (m == l) {            // label 130
                    SD(l, p); --l;
                    if (l >= lend) continue;
                    break;
                }
                if (m == l - 1) {
                    float rt1, rt2, c, s;
                    slaev2_(GD(l - 1), GE(l - 1), GD(l), rt1, rt2, c, s);
                    ZR(l - 1, c, s);
                    SD(l - 1, rt1); SD(l, rt2); SE(l - 1, 0.0f);
                    l -= 2;
                    if (l >= lend) continue;
                    break;
                }
                if (jtot == nmaxit) break;
                ++jtot;
                {
                    float el = GE(l - 1);
                    float g = (GD(l - 1) - p) / (2.0f * el);
                    float r = slapy2_(g, 1.0f);
                    g = GD(m) - p + el / (g + ((g >= 0.0f) ? r : -r));
                    float s = 1.0f, c = 1.0f;
                    p = 0.0f;
                    for (int i = m; i <= l - 1; ++i) {
                        float ei = GE(i);
                        float f = s * ei;
                        float b = c * ei;
                        slartg_(g, f, c, s, r);
                        if (i != m) SE(i - 1, r);
                        g = GD(i) - p;
                        float r2 = ((GD(i + 1) - g) * s) + ((2.0f * c) * b);
                        p = s * r2;
                        SD(i, g + p);
                        g = (c * r2) - b;
                        ZR(i, c, s);     // QR stores +s
                    }
                    SD(l, GD(l) - p);
                    SE(l - 1, g);
                }
            }
        }
    }
    // label 160: selection sort ascending + eigenvector column swaps (n=3).
    {
        int k = 1; float p = d1_;
        if (d2_ < p) { k = 2; p = d2_; }
        if (d3_ < p) { k = 3; p = d3_; }
        if (k == 2) {
            d2_ = d1_; d1_ = p;
            float t;
            t = z11; z11 = z12; z12 = t;
            t = z21; z21 = z22; z22 = t;
            t = z31; z31 = z32; z32 = t;
        } else if (k == 3) {
            d3_ = d1_; d1_ = p;
            float t;
            t = z11; z11 = z13; z13 = t;
            t = z21; z21 = z23; z23 = t;
            t = z31; z31 = z33; z33 = t;
        }
        if (d3_ < d2_) {
            float t = d2_; d2_ = d3_; d3_ = t;
            t = z12; z12 = z13; z13 = t;
            t = z22; z22 = z23; z23 = t;
            t = z32; z32 = z33; z33 = t;
        }
    }
#undef GD
#undef SD
#undef GE
#undef SE
#undef ZR
}

__device__ __forceinline__ float nrm3_(float x, float y, float z) {
    _Pragma("clang fp contract(off)")
    float t = (x * x) + (y * y);    // np order ((x*x + y*y) + z*z), no FMA
    t = t + (z * z);
    return sqrtf(t);
}

__device__ __forceinline__ void covstep(float px, float py, float pz, float nrm,
                                        float mx, float denom,
                                        float &c00, float &c10, float &c20,
                                        float &c11, float &c21, float &c22) {
    _Pragma("clang fp contract(off)")
    const float w  = mx - nrm;
    const float wq = w / denom;
    const float spx = 100.0f * px, spy = 100.0f * py, spz = 100.0f * pz;
    const float ax = wq * spx, ay = wq * spy, az = wq * spz;
    c00 = c00 + (ax * spx);
    c10 = c10 + (ay * spx);
    c20 = c20 + (az * spx);
    c11 = c11 + (ay * spy);
    c21 = c21 + (az * spy);
    c22 = c22 + (az * spz);
}

__device__ __forceinline__ void projstep(float px, float py, float pz,
                                         float zv0, float zv1, float zv2,
                                         float xv0, float xv1, float xv2,
                                         int &cz, int &cx) {
    _Pragma("clang fp contract(off)")
    const float pjz = ((zv0 * px) + (zv1 * py)) + (zv2 * pz);
    const float pjx = ((xv0 * px) + (xv1 * py)) + (xv2 * pz);
    cz += (pjz > 0.0f) ? 1 : 0;
    cx += (pjx > 0.0f) ? 1 : 0;
}

__device__ __forceinline__ void rotstep(float px, float py, float pz,
                                        float zv0, float zv1, float zv2,
                                        float yv0, float yv1, float yv2,
                                        float xv0, float xv1, float xv2,
                                        float &ra, float &rb, float &rc) {
    _Pragma("clang fp contract(off)")
    ra = ((px * zv0) + (py * zv1)) + (pz * zv2);
    rb = ((px * yv0) + (py * yv1)) + (pz * yv2);
    rc = ((px * xv0) + (py * xv1)) + (pz * xv2);
}

__global__ __launch_bounds__(64, 2) void lrf_kernel(const float* __restrict__ nbr,
                                                    float* __restrict__ rot,
                                                    float* __restrict__ lrf) {
    _Pragma("clang fp contract(off)")
    // 64 threads/block, 1 group per thread. Norm cache: 64 norms/thread in LDS,
    // stride 65 dwords -> lanes hit banks (t+s)%32, 2 lanes/bank = conflict-free.
    __shared__ float nlds[64 * 65];
    const int tid = threadIdx.x;
    const int g = (blockIdx.x << 6) + tid;                 // 0..131071
    const float4* __restrict__ p4 = reinterpret_cast<const float4*>(nbr) + g * 48;
    const int tb = tid * 65;

    // ---- pass 1: norms -> LDS, exact order-free max over 64 ----
    float mx = -3.402823466e+38f;
#pragma unroll 4
    for (int q = 0; q < 16; ++q) {
        const float4 v0 = p4[q * 3 + 0];
        const float4 v1 = p4[q * 3 + 1];
        const float4 v2 = p4[q * 3 + 2];
        const float n0 = nrm3_(v0.x, v0.y, v0.z);
        const float n1 = nrm3_(v0.w, v1.x, v1.y);
        const float n2 = nrm3_(v1.z, v1.w, v2.x);
        const float n3 = nrm3_(v2.y, v2.z, v2.w);
        nlds[tb + 4 * q + 0] = n0;
        nlds[tb + 4 * q + 1] = n1;
        nlds[tb + 4 * q + 2] = n2;
        nlds[tb + 4 * q + 3] = n3;
        mx = fmaxf(mx, fmaxf(fmaxf(n0, n1), fmaxf(n2, n3)));
    }

    // ---- pass 2 (LDS only): np.sum pairwise order for n=64:
    // r_j = w_j + w_{j+8} + ... + w_{j+56} sequential, then
    // ws = ((r0+r1)+(r2+r3)) + ((r4+r5)+(r6+r7)).
    float r0 = 0.0f, r1 = 0.0f, r2 = 0.0f, r3 = 0.0f,
          r4 = 0.0f, r5 = 0.0f, r6 = 0.0f, r7 = 0.0f;
#pragma unroll
    for (int k = 0; k < 8; ++k) {
        const int b = tb + 8 * k;
        r0 = r0 + (mx - nlds[b + 0]);
        r1 = r1 + (mx - nlds[b + 1]);
        r2 = r2 + (mx - nlds[b + 2]);
        r3 = r3 + (mx - nlds[b + 3]);
        r4 = r4 + (mx - nlds[b + 4]);
        r5 = r5 + (mx - nlds[b + 5]);
        r6 = r6 + (mx - nlds[b + 6]);
        r7 = r7 + (mx - nlds[b + 7]);
    }
    const float ws = ((r0 + r1) + (r2 + r3)) + ((r4 + r5) + (r6 + r7));
    const float denom = ws + 1e-6f;

    // ---- pass 3: covariance, sequential ascending s, per-product rounding.
    // Lower triangle: C[k,l] = sum_s A[s,k]*B[s,l], A = w*scaled_pos, B = scaled_pos.
    float c00 = 0.0f, c10 = 0.0f, c20 = 0.0f, c11 = 0.0f, c21 = 0.0f, c22 = 0.0f;
#pragma unroll 4
    for (int q = 0; q < 16; ++q) {
        const float4 v0 = p4[q * 3 + 0];
        const float4 v1 = p4[q * 3 + 1];
        const float4 v2 = p4[q * 3 + 2];
        covstep(v0.x, v0.y, v0.z, nlds[tb + 4 * q + 0], mx, denom, c00, c10, c20, c11, c21, c22);
        covstep(v0.w, v1.x, v1.y, nlds[tb + 4 * q + 1], mx, denom, c00, c10, c20, c11, c21, c22);
        covstep(v1.z, v1.w, v2.x, nlds[tb + 4 * q + 2], mx, denom, c00, c10, c20, c11, c21, c22);
        covstep(v2.y, v2.z, v2.w, nlds[tb + 4 * q + 3], mx, denom, c00, c10, c20, c11, c21, c22);
    }

    const float a11 = c00, a21 = c10, a31 = c20, a22 = c11, a32 = c21, a33 = c22;

    // --- ssytd2 (UPLO='L', n=3), exact reference-BLAS op order ---
    float taui, v2h, e1q, d2q, d3q, e2q;
    const float xnorm = fabsf(a31);   // snrm2(1,x)
    if (xnorm == 0.0f) {
        taui = 0.0f; v2h = a31; e1q = a21; d2q = a22; e2q = a32; d3q = a33;
    } else {
        const float beta = -copysignf(slapy2_(a21, xnorm), a21);
        taui = (beta - a21) / beta;
        const float rcp = 1.0f / (a21 - beta);   // sscal multiplies by reciprocal
        v2h = a31 * rcp;
        e1q = beta;
        // ssymv (reference order), alpha=taui, x=(1,v2), y:=0:
        float x1 = taui * a22;
        float x2 = taui * a32;
        const float temp2 = a32 * v2h;
        x1 = x1 + (taui * temp2);
        const float t1v = taui * v2h;
        x2 = x2 + (t1v * a33);
        const float dt = x1 + (x2 * v2h);        // sdot sequential
        const float alpha_c = (-0.5f * taui) * dt;
        const float w1 = x1 + alpha_c;           // saxpy
        const float w2 = x2 + (alpha_c * v2h);
        d2q = (a22 - w1) - w1;                   // ssyr2 alpha=-1, reference order
        e2q = (a32 - (v2h * w1)) - w2;
        d3q = (a33 - (v2h * w2)) - (w2 * v2h);
    }

    float d1_ = a11, d2_ = d2q, d3_ = d3q, e1_ = e1q, e2_ = e2q;
    float z11 = 1.0f, z12 = 0.0f, z13 = 0.0f;
    float z21 = 0.0f, z22 = 1.0f, z23 = 0.0f;
    float z31 = 0.0f, z32 = 0.0f, z33 = 1.0f;
    ssteqr3_reg(d1_, d2_, d3_, e1_, e2_,
                z11, z12, z13, z21, z22, z23, z31, z32, z33);

    // --- sormtr/sorm2r/slarf: apply H = I - tau*v*v' to columns 1 and 3 ---
    float zv0, zv1, zv2, xv0, xv1, xv2;
    {
        const float u2 = z21, u3 = z31;
        zv0 = z11;
        if (taui != 0.0f) {
            const float wj = u2 + (u3 * v2h);   // sgemv 'T'
            const float pj = taui * wj;         // sger
            zv1 = u2 - pj;
            zv2 = u3 - (v2h * pj);
        } else { zv1 = u2; zv2 = u3; }
    }
    {
        const float u2 = z23, u3 = z33;
        xv0 = z13;
        if (taui != 0.0f) {
            const float wj = u2 + (u3 * v2h);
            const float pj = taui * wj;
            xv1 = u2 - pj;
            xv2 = u3 - (v2h * pj);
        } else { xv1 = u2; xv2 = u3; }
    }

    // ---- pass 4: sign disambiguation counts (proj with unflipped axes;
    // x-proj never involves z, so counting both first == reference order) ----
    int cz = 0, cx = 0;
#pragma unroll 4
    for (int q = 0; q < 16; ++q) {
        const float4 v0 = p4[q * 3 + 0];
        const float4 v1 = p4[q * 3 + 1];
        const float4 v2 = p4[q * 3 + 2];
        projstep(v0.x, v0.y, v0.z, zv0, zv1, zv2, xv0, xv1, xv2, cz, cx);
        projstep(v0.w, v1.x, v1.y, zv0, zv1, zv2, xv0, xv1, xv2, cz, cx);
        projstep(v1.z, v1.w, v2.x, zv0, zv1, zv2, xv0, xv1, xv2, cz, cx);
        projstep(v2.y, v2.z, v2.w, zv0, zv1, zv2, xv0, xv1, xv2, cz, cx);
    }
    if (cz < 32) { zv0 = -zv0; zv1 = -zv1; zv2 = -zv2; }
    if (cx < 32) { xv0 = -xv0; xv1 = -xv1; xv2 = -xv2; }

    // y = cross(z, x), per-op rounding
    const float yv0 = (zv1 * xv2) - (zv2 * xv1);
    const float yv1 = (zv2 * xv0) - (zv0 * xv2);
    const float yv2 = (zv0 * xv1) - (zv1 * xv0);

    // ---- pass 5: rot[s,d] = (p0*L[0,d] + p1*L[1,d]) + p2*L[2,d], cols (z,y,x) ----
    float4* __restrict__ o4 = reinterpret_cast<float4*>(rot) + g * 48;
#pragma unroll 4
    for (int q = 0; q < 16; ++q) {
        const float4 v0 = p4[q * 3 + 0];
        const float4 v1 = p4[q * 3 + 1];
        const float4 v2 = p4[q * 3 + 2];
        float r0a, r0b, r0c, r1a, r1b, r1c, r2a, r2b, r2c, r3a, r3b, r3c;
        rotstep(v0.x, v0.y, v0.z, zv0, zv1, zv2, yv0, yv1, yv2, xv0, xv1, xv2, r0a, r0b, r0c);
        rotstep(v0.w, v1.x, v1.y, zv0, zv1, zv2, yv0, yv1, yv2, xv0, xv1, xv2, r1a, r1b, r1c);
        rotstep(v1.z, v1.w, v2.x, zv0, zv1, zv2, yv0, yv1, yv2, xv0, xv1, xv2, r2a, r2b, r2c);
        rotstep(v2.y, v2.z, v2.w, zv0, zv1, zv2, yv0, yv1, yv2, xv0, xv1, xv2, r3a, r3b, r3c);
        float4 o0, o1, o2;
        o0.x = r0a; o0.y = r0b; o0.z = r0c; o0.w = r1a;
        o1.x = r1b; o1.y = r1c; o1.z = r2a; o1.w = r2b;
        o2.x = r2c; o2.y = r3a; o2.z = r3b; o2.w = r3c;
        o4[q * 3 + 0] = o0;
        o4[q * 3 + 1] = o1;
        o4[q * 3 + 2] = o2;
    }

    // lrfs[c][d]: c = component, d selects (z,y,x)
    float* __restrict__ lp = lrf + g * 9;
    lp[0] = zv0; lp[1] = yv0; lp[2] = xv0;
    lp[3] = zv1; lp[4] = yv1; lp[5] = xv1;
    lp[6] = zv2; lp[7] = yv2; lp[8] = xv2;
}

extern "C" void kernel_launch(void* const* d_in, const int* in_sizes, int n_in,
                              void* d_out, int out_size, void* d_ws, size_t ws_size,
                              hipStream_t stream) {
    const float* neighbor = (const float*)d_in[0];
    // d_in[1] (center) is unused by the reference computation.
    float* rot = (float*)d_out;                                  // (B,G,S,3)
    float* lrf = (float*)d_out + (long long)64 * 2048 * 64 * 3;  // (B,G,3,3)

    lrf_kernel<<<dim3(2048), dim3(64), 0, stream>>>(neighbor, rot, lrf);
}

// Round 2
// 274.834 us; speedup vs baseline: 3.5445x; 1.0910x over previous
//
#include <hip/hip_runtime.h>
#include <math.h>

// B=64, G=2048, S=64, C=3 -> 131072 groups.
// 4-lane-cluster-per-group: order-free phases (norms, max, sign counts,
// per-sample wq, rot) are split across 4 lanes; order-sensitive phases
// (pairwise weight sum, sequential covariance, eigen solve) keep the exact
// reference rounding order (ws via exact-pair shfl tree; cov + eigen run
// redundantly on all 4 lanes). Outputs are bit-identical to the previous
// thread-per-group kernel; wave count rises 4x (2048 -> 8192 waves).

__device__ __forceinline__ float slapy2_(float x, float y) {
    _Pragma("clang fp contract(off)")
    float xa = fabsf(x), ya = fabsf(y);
    float w = fmaxf(xa, ya), z = fminf(xa, ya);
    if (z == 0.0f) return w;
    float t = z / w;
    return w * sqrtf(1.0f + t * t);
}

// LAPACK >= 3.10 slartg (fast path; magnitudes mid-range).
__device__ __forceinline__ void slartg_(float f, float g,
                                        float &c, float &s, float &r) {
    _Pragma("clang fp contract(off)")
    if (g == 0.0f) { c = 1.0f; s = 0.0f; r = f; return; }
    if (f == 0.0f) { c = 0.0f; s = (g >= 0.0f) ? 1.0f : -1.0f; r = fabsf(g); return; }
    float d = sqrtf(f * f + g * g);
    float p = 1.0f / d;
    c = fabsf(f) * p;
    s = g * ((f >= 0.0f) ? p : -p);
    r = (f >= 0.0f) ? d : -d;
}

__device__ __forceinline__ void slaev2_(float a, float b, float cc,
                                        float &rt1, float &rt2,
                                        float &cs1, float &sn1) {
    _Pragma("clang fp contract(off)")
    float sm = a + cc, df = a - cc;
    float adf = fabsf(df);
    float tb = b + b;
    float ab = fabsf(tb);
    float acmx, acmn;
    if (fabsf(a) > fabsf(cc)) { acmx = a; acmn = cc; } else { acmx = cc; acmn = a; }
    float rt;
    if (adf > ab)      { float t = ab / adf; rt = adf * sqrtf(1.0f + t * t); }
    else if (adf < ab) { float t = adf / ab; rt = ab * sqrtf(1.0f + t * t); }
    else                rt = ab * sqrtf(2.0f);
    int sgn1;
    if (sm < 0.0f)      { rt1 = 0.5f * (sm - rt); sgn1 = -1; rt2 = (acmx / rt1) * acmn - (b / rt1) * b; }
    else if (sm > 0.0f) { rt1 = 0.5f * (sm + rt); sgn1 =  1; rt2 = (acmx / rt1) * acmn - (b / rt1) * b; }
    else                { rt1 = 0.5f * rt; rt2 = -0.5f * rt; sgn1 = 1; }
    int sgn2;
    float cs;
    if (df >= 0.0f) { cs = df + rt; sgn2 = 1; } else { cs = df - rt; sgn2 = -1; }
    float acs = fabsf(cs);
    if (acs > ab) {
        float ct = -tb / cs;
        sn1 = 1.0f / sqrtf(1.0f + ct * ct);
        cs1 = ct * sn1;
    } else {
        if (ab == 0.0f) { cs1 = 1.0f; sn1 = 0.0f; }
        else {
            float tn = -cs / tb;
            cs1 = 1.0f / sqrtf(1.0f + tn * tn);
            sn1 = tn * cs1;
        }
    }
    if (sgn1 == sgn2) { float tn = cs1; cs1 = -sn1; sn1 = tn; }
}

// --- register-resident accessors for 1-based d[1..3], e[1..2] (cndmask, no scratch) ---
__device__ __forceinline__ float getd3(int i, float d1, float d2, float d3) {
    return (i == 1) ? d1 : ((i == 2) ? d2 : d3);
}
__device__ __forceinline__ void setd3(int i, float v, float &d1, float &d2, float &d3) {
    d1 = (i == 1) ? v : d1;
    d2 = (i == 2) ? v : d2;
    d3 = (i == 3) ? v : d3;
}
__device__ __forceinline__ float gete2(int i, float e1, float e2) {
    return (i == 1) ? e1 : e2;
}
__device__ __forceinline__ void sete2(int i, float v, float &e1, float &e2) {
    e1 = (i == 1) ? v : e1;
    e2 = (i == 2) ? v : e2;
}

// slasr single rotation on columns (j, j+1), j in {1,2}; exact reference formula.
__device__ __forceinline__ void zrot3r(int j, float ctemp, float stemp,
                                       float &z11, float &z12, float &z13,
                                       float &z21, float &z22, float &z23,
                                       float &z31, float &z32, float &z33) {
    _Pragma("clang fp contract(off)")
    if (j == 1) {
        { float t = z12; z12 = (ctemp * t) - (stemp * z11); z11 = (stemp * t) + (ctemp * z11); }
        { float t = z22; z22 = (ctemp * t) - (stemp * z21); z21 = (stemp * t) + (ctemp * z21); }
        { float t = z32; z32 = (ctemp * t) - (stemp * z31); z31 = (stemp * t) + (ctemp * z31); }
    } else {
        { float t = z13; z13 = (ctemp * t) - (stemp * z12); z12 = (stemp * t) + (ctemp * z12); }
        { float t = z23; z23 = (ctemp * t) - (stemp * z22); z22 = (stemp * t) + (ctemp * z22); }
        { float t = z33; z33 = (ctemp * t) - (stemp * z32); z32 = (stemp * t) + (ctemp * z32); }
    }
}

// ssteqr('I') n=3, faithful LAPACK control flow, all state in registers.
__device__ __forceinline__ void ssteqr3_reg(
        float &d1_, float &d2_, float &d3_, float &e1_, float &e2_,
        float &z11, float &z12, float &z13,
        float &z21, float &z22, float &z23,
        float &z31, float &z32, float &z33) {
    _Pragma("clang fp contract(off)")
    const float EPS    = 5.9604644775390625e-8f;   // slamch('E') = 2^-24
    const float EPS2   = EPS * EPS;
    const float SAFMIN = 1.17549435e-38f;
    const int n = 3, nmaxit = 3 * 30;
    int jtot = 0, l1 = 1;

#define GD(i)      getd3((i), d1_, d2_, d3_)
#define SD(i, v)   setd3((i), (v), d1_, d2_, d3_)
#define GE(i)      gete2((i), e1_, e2_)
#define SE(i, v)   sete2((i), (v), e1_, e2_)
#define ZR(j, c, s) zrot3r((j), (c), (s), z11, z12, z13, z21, z22, z23, z31, z32, z33)

    while (true) {                       // label 10
        if (l1 > n) break;
        if (l1 > 1) SE(l1 - 1, 0.0f);
        int m = n;
        for (int mm = l1; mm <= n - 1; ++mm) {
            float tst = fabsf(GE(mm));
            if (tst == 0.0f) { m = mm; break; }
            if (tst <= (sqrtf(fabsf(GD(mm))) * sqrtf(fabsf(GD(mm + 1)))) * EPS) {
                SE(mm, 0.0f); m = mm; break;
            }
        }
        int l = l1, lsv = l, lend = m, lendsv = lend;
        l1 = m + 1;
        if (lend == l) continue;
        // slascl scaling skipped: block norms ~1e2..1e4, inside [ssfmin, ssfmax]
        if (fabsf(GD(lend)) < fabsf(GD(l))) { lend = lsv; l = lendsv; }

        if (lend > l) {
            // ---- QL ----
            while (true) {               // label 40
                m = lend;
                if (l != lend) {
                    for (int mm = l; mm <= lend - 1; ++mm) {
                        float em = GE(mm);
                        float tst = em * em;
                        if (tst <= (EPS2 * fabsf(GD(mm))) * fabsf(GD(mm + 1)) + SAFMIN) { m = mm; break; }
                    }
                }
                if (m < lend) SE(m, 0.0f);
                float p = GD(l);
                if (m == l) {            // label 80
                    SD(l, p); ++l;
                    if (l <= lend) continue;
                    break;
                }
                if (m == l + 1) {
                    float rt1, rt2, c, s;
                    slaev2_(GD(l), GE(l), GD(l + 1), rt1, rt2, c, s);
                    ZR(l, c, s);
                    SD(l, rt1); SD(l + 1, rt2); SE(l, 0.0f);
                    l += 2;
                    if (l <= lend) continue;
                    break;
                }
                if (jtot == nmaxit) break;
                ++jtot;
                {
                    float el = GE(l);
                    float g = (GD(l + 1) - p) / (2.0f * el);
                    float r = slapy2_(g, 1.0f);
                    g = GD(m) - p + el / (g + ((g >= 0.0f) ? r : -r));  // sign(r,g)
                    float s = 1.0f, c = 1.0f;
                    p = 0.0f;
                    for (int i = m - 1; i >= l; --i) {
                        float ei = GE(i);
                        float f = s * ei;
                        float b = c * ei;
                        slartg_(g, f, c, s, r);
                        if (i != m - 1) SE(i + 1, r);
                        g = GD(i + 1) - p;
                        float r2 = ((GD(i) - g) * s) + ((2.0f * c) * b);
                        p = s * r2;
                        SD(i + 1, g + p);
                        g = (c * r2) - b;
                        ZR(i, c, -s);    // QL stores -s
                    }
                    SD(l, GD(l) - p);
                    SE(l, g);
                }
            }
        } else if (lend < l) {
            // ---- QR ----
            while (true) {               // label 90
                m = lend;
                if (l != lend) {
                    for (int mm = l; mm >= lend + 1; --mm) {
                        float em = GE(mm - 1);
                        float tst = em * em;
                        if (tst <= (EPS2 * fabsf(GD(mm))) * fabsf(GD(mm - 1)) + SAFMIN) { m = mm; break; }
                    }
                }
                if (m > lend) SE(m - 1, 0.0f);
                float p = GD(l);
                if (m == l) {            // label 130
                    SD(l, p); --l;
                    if (l >= lend) continue;
                    break;
                }
                if (m == l - 1) {
                    float rt1, rt2, c, s;
                    slaev2_(GD(l - 1), GE(l - 1), GD(l), rt1, rt2, c, s);
                    ZR(l - 1, c, s);
                    SD(l - 1, rt1); SD(l, rt2); SE(l - 1, 0.0f);
                    l -= 2;
                    if (l >= lend) continue;
                    break;
                }
                if (jtot == nmaxit) break;
                ++jtot;
                {
                    float el = GE(l - 1);
                    float g = (GD(l - 1) - p) / (2.0f * el);
                    float r = slapy2_(g, 1.0f);
                    g = GD(m) - p + el / (g + ((g >= 0.0f) ? r : -r));
                    float s = 1.0f, c = 1.0f;
                    p = 0.0f;
                    for (int i = m; i <= l - 1; ++i) {
                        float ei = GE(i);
                        float f = s * ei;
                        float b = c * ei;
                        slartg_(g, f, c, s, r);
                        if (i != m) SE(i - 1, r);
                        g = GD(i) - p;
                        float r2 = ((GD(i + 1) - g) * s) + ((2.0f * c) * b);
                        p = s * r2;
                        SD(i, g + p);
                        g = (c * r2) - b;
                        ZR(i, c, s);     // QR stores +s
                    }
                    SD(l, GD(l) - p);
                    SE(l - 1, g);
                }
            }
        }
    }
    // label 160: selection sort ascending + eigenvector column swaps (n=3).
    {
        int k = 1; float p = d1_;
        if (d2_ < p) { k = 2; p = d2_; }
        if (d3_ < p) { k = 3; p = d3_; }
        if (k == 2) {
            d2_ = d1_; d1_ = p;
            float t;
            t = z11; z11 = z12; z12 = t;
            t = z21; z21 = z22; z22 = t;
            t = z31; z31 = z32; z32 = t;
        } else if (k == 3) {
            d3_ = d1_; d1_ = p;
            float t;
            t = z11; z11 = z13; z13 = t;
            t = z21; z21 = z23; z23 = t;
            t = z31; z31 = z33; z33 = t;
        }
        if (d3_ < d2_) {
            float t = d2_; d2_ = d3_; d3_ = t;
            t = z12; z12 = z13; z13 = t;
            t = z22; z22 = z23; z23 = t;
            t = z32; z32 = z33; z33 = t;
        }
    }
#undef GD
#undef SD
#undef GE
#undef SE
#undef ZR
}

__device__ __forceinline__ float nrm3_(float x, float y, float z) {
    _Pragma("clang fp contract(off)")
    float t = (x * x) + (y * y);    // np order ((x*x + y*y) + z*z), no FMA
    t = t + (z * z);
    return sqrtf(t);
}

// cov accumulation step; wq precomputed as (mx - nrm)/denom (identical value).
__device__ __forceinline__ void covstep(float px, float py, float pz, float wq,
                                        float &c00, float &c10, float &c20,
                                        float &c11, float &c21, float &c22) {
    _Pragma("clang fp contract(off)")
    const float spx = 100.0f * px, spy = 100.0f * py, spz = 100.0f * pz;
    const float ax = wq * spx, ay = wq * spy, az = wq * spz;
    c00 = c00 + (ax * spx);
    c10 = c10 + (ay * spx);
    c20 = c20 + (az * spx);
    c11 = c11 + (ay * spy);
    c21 = c21 + (az * spy);
    c22 = c22 + (az * spz);
}

__device__ __forceinline__ void rotstep(float px, float py, float pz,
                                        float zv0, float zv1, float zv2,
                                        float yv0, float yv1, float yv2,
                                        float xv0, float xv1, float xv2,
                                        float &ra, float &rb, float &rc) {
    _Pragma("clang fp contract(off)")
    ra = ((px * zv0) + (py * zv1)) + (pz * zv2);
    rb = ((px * yv0) + (py * yv1)) + (pz * yv2);
    rc = ((px * xv0) + (py * xv1)) + (pz * xv2);
}

__global__ __launch_bounds__(256, 4) void lrf_kernel(const float* __restrict__ nbr,
                                                     float* __restrict__ rot,
                                                     float* __restrict__ lrf) {
    _Pragma("clang fp contract(off)")
    // 256 threads = 64 groups/block, 4-lane cluster per group.
    // LDS: per group 64 floats (norms, then overwritten with wq), stride 65.
    __shared__ float wql[64 * 65];
    const int tid = threadIdx.x;
    const int gl  = tid >> 2;               // group-local 0..63
    const int k   = tid & 3;                // cluster lane 0..3
    const int g   = (blockIdx.x << 6) + gl; // global group id
    const int lbase = gl * 65;

    const float4* __restrict__ p4 = reinterpret_cast<const float4*>(nbr)
                                    + (long long)g * 48 + k * 12;   // own 16 samples
    const float4* __restrict__ q4 = reinterpret_cast<const float4*>(nbr)
                                    + (long long)g * 48;            // full group

    // ---- pass 1: own 16 norms -> LDS; cluster max (order-free exact) ----
    float mx = -3.402823466e+38f;
#pragma unroll
    for (int q = 0; q < 4; ++q) {
        const float4 v0 = p4[q * 3 + 0];
        const float4 v1 = p4[q * 3 + 1];
        const float4 v2 = p4[q * 3 + 2];
        const float n0 = nrm3_(v0.x, v0.y, v0.z);
        const float n1 = nrm3_(v0.w, v1.x, v1.y);
        const float n2 = nrm3_(v1.z, v1.w, v2.x);
        const float n3 = nrm3_(v2.y, v2.z, v2.w);
        const int b = lbase + 16 * k + 4 * q;
        wql[b + 0] = n0;
        wql[b + 1] = n1;
        wql[b + 2] = n2;
        wql[b + 3] = n3;
        mx = fmaxf(mx, fmaxf(fmaxf(n0, n1), fmaxf(n2, n3)));
    }
    mx = fmaxf(mx, __shfl_xor(mx, 1, 64));
    mx = fmaxf(mx, __shfl_xor(mx, 2, 64));
    __builtin_amdgcn_wave_barrier();
    asm volatile("" ::: "memory");

    // ---- pass 2: exact pairwise weight sum.
    // Reference: q_j = w_j + w_{j+8} + ... (t ascending), ws = ((q0+q1)+(q2+q3))
    // + ((q4+q5)+(q6+q7)). Lane k computes q_{2k}, q_{2k+1}; shfl tree matches
    // the exact pairing (FP add commutative bitwise).
    float r0_ = 0.0f, r1_ = 0.0f;
    {
        const int j0 = lbase + 2 * k;
#pragma unroll
        for (int t = 0; t < 8; ++t) {
            r0_ = r0_ + (mx - wql[j0 + 8 * t + 0]);
            r1_ = r1_ + (mx - wql[j0 + 8 * t + 1]);
        }
    }
    const float A_ = r0_ + r1_;
    const float B_ = A_ + __shfl_xor(A_, 1, 64);
    const float ws = B_ + __shfl_xor(B_, 2, 64);
    const float denom = ws + 1e-6f;
    asm volatile("" ::: "memory");

    // ---- pass 2b: overwrite own norm slots with wq = (mx-nrm)/denom ----
#pragma unroll
    for (int i = 0; i < 16; ++i) {
        const int idx = lbase + 16 * k + i;
        const float nv = wql[idx];
        wql[idx] = (mx - nv) / denom;
    }
    __builtin_amdgcn_wave_barrier();
    asm volatile("" ::: "memory");

    // ---- pass 3: covariance, strict sequential s=0..63 (redundant on all 4
    // lanes; same-address loads broadcast within the cluster). ----
    float c00 = 0.0f, c10 = 0.0f, c20 = 0.0f, c11 = 0.0f, c21 = 0.0f, c22 = 0.0f;
#pragma unroll 4
    for (int q = 0; q < 16; ++q) {
        const float4 v0 = q4[q * 3 + 0];
        const float4 v1 = q4[q * 3 + 1];
        const float4 v2 = q4[q * 3 + 2];
        const float w0 = wql[lbase + 4 * q + 0];
        const float w1 = wql[lbase + 4 * q + 1];
        const float w2 = wql[lbase + 4 * q + 2];
        const float w3 = wql[lbase + 4 * q + 3];
        covstep(v0.x, v0.y, v0.z, w0, c00, c10, c20, c11, c21, c22);
        covstep(v0.w, v1.x, v1.y, w1, c00, c10, c20, c11, c21, c22);
        covstep(v1.z, v1.w, v2.x, w2, c00, c10, c20, c11, c21, c22);
        covstep(v2.y, v2.z, v2.w, w3, c00, c10, c20, c11, c21, c22);
    }

    const float a11 = c00, a21 = c10, a31 = c20, a22 = c11, a32 = c21, a33 = c22;

    // --- ssytd2 (UPLO='L', n=3), exact reference-BLAS op order ---
    float taui, v2h, e1q, d2q, d3q, e2q;
    const float xnorm = fabsf(a31);   // snrm2(1,x)
    if (xnorm == 0.0f) {
        taui = 0.0f; v2h = a31; e1q = a21; d2q = a22; e2q = a32; d3q = a33;
    } else {
        const float beta = -copysignf(slapy2_(a21, xnorm), a21);
        taui = (beta - a21) / beta;
        const float rcp = 1.0f / (a21 - beta);   // sscal multiplies by reciprocal
        v2h = a31 * rcp;
        e1q = beta;
        // ssymv (reference order), alpha=taui, x=(1,v2), y:=0:
        float x1 = taui * a22;
        float x2 = taui * a32;
        const float temp2 = a32 * v2h;
        x1 = x1 + (taui * temp2);
        const float t1v = taui * v2h;
        x2 = x2 + (t1v * a33);
        const float dt = x1 + (x2 * v2h);        // sdot sequential
        const float alpha_c = (-0.5f * taui) * dt;
        const float w1 = x1 + alpha_c;           // saxpy
        const float w2 = x2 + (alpha_c * v2h);
        d2q = (a22 - w1) - w1;                   // ssyr2 alpha=-1, reference order
        e2q = (a32 - (v2h * w1)) - w2;
        d3q = (a33 - (v2h * w2)) - (w2 * v2h);
    }

    float d1_ = a11, d2_ = d2q, d3_ = d3q, e1_ = e1q, e2_ = e2q;
    float z11 = 1.0f, z12 = 0.0f, z13 = 0.0f;
    float z21 = 0.0f, z22 = 1.0f, z23 = 0.0f;
    float z31 = 0.0f, z32 = 0.0f, z33 = 1.0f;
    ssteqr3_reg(d1_, d2_, d3_, e1_, e2_,
                z11, z12, z13, z21, z22, z23, z31, z32, z33);

    // --- sormtr/sorm2r/slarf: apply H = I - tau*v*v' to columns 1 and 3 ---
    float zv0, zv1, zv2, xv0, xv1, xv2;
    {
        const float u2 = z21, u3 = z31;
        zv0 = z11;
        if (taui != 0.0f) {
            const float wj = u2 + (u3 * v2h);   // sgemv 'T'
            const float pj = taui * wj;         // sger
            zv1 = u2 - pj;
            zv2 = u3 - (v2h * pj);
        } else { zv1 = u2; zv2 = u3; }
    }
    {
        const float u2 = z23, u3 = z33;
        xv0 = z13;
        if (taui != 0.0f) {
            const float wj = u2 + (u3 * v2h);
            const float pj = taui * wj;
            xv1 = u2 - pj;
            xv2 = u3 - (v2h * pj);
        } else { xv1 = u2; xv2 = u3; }
    }

    // y0 = cross(z0, x0) unflipped; final y = (sz*sx)*y0 is bitwise equal to
    // the reference's cross of flipped axes (sign flips are exact in *, -).
    const float yv0 = (zv1 * xv2) - (zv2 * xv1);
    const float yv1 = (zv2 * xv0) - (zv0 * xv2);
    const float yv2 = (zv0 * xv1) - (zv1 * xv0);

    // ---- pass 4+5 fused: per-sample unflipped (p.z0, p.y0, p.x0) held in
    // registers (static indices), exact integer sign counts, then +-1 scale
    // (bitwise-exact negation) and coalesced store. ----
    float fr[48];
    int cz = 0, cx = 0;
#pragma unroll
    for (int q = 0; q < 4; ++q) {
        const float4 v0 = p4[q * 3 + 0];
        const float4 v1 = p4[q * 3 + 1];
        const float4 v2 = p4[q * 3 + 2];
        rotstep(v0.x, v0.y, v0.z, zv0, zv1, zv2, yv0, yv1, yv2, xv0, xv1, xv2,
                fr[12 * q + 0], fr[12 * q + 1], fr[12 * q + 2]);
        rotstep(v0.w, v1.x, v1.y, zv0, zv1, zv2, yv0, yv1, yv2, xv0, xv1, xv2,
                fr[12 * q + 3], fr[12 * q + 4], fr[12 * q + 5]);
        rotstep(v1.z, v1.w, v2.x, zv0, zv1, zv2, yv0, yv1, yv2, xv0, xv1, xv2,
                fr[12 * q + 6], fr[12 * q + 7], fr[12 * q + 8]);
        rotstep(v2.y, v2.z, v2.w, zv0, zv1, zv2, yv0, yv1, yv2, xv0, xv1, xv2,
                fr[12 * q + 9], fr[12 * q + 10], fr[12 * q + 11]);
        cz += (fr[12 * q + 0] > 0.0f) ? 1 : 0;
        cz += (fr[12 * q + 3] > 0.0f) ? 1 : 0;
        cz += (fr[12 * q + 6] > 0.0f) ? 1 : 0;
        cz += (fr[12 * q + 9] > 0.0f) ? 1 : 0;
        cx += (fr[12 * q + 2] > 0.0f) ? 1 : 0;
        cx += (fr[12 * q + 5] > 0.0f) ? 1 : 0;
        cx += (fr[12 * q + 8] > 0.0f) ? 1 : 0;
        cx += (fr[12 * q + 11] > 0.0f) ? 1 : 0;
    }
    cz += __shfl_xor(cz, 1, 64);
    cz += __shfl_xor(cz, 2, 64);
    cx += __shfl_xor(cx, 1, 64);
    cx += __shfl_xor(cx, 2, 64);
    const float sz = (cz < 32) ? -1.0f : 1.0f;
    const float sx = (cx < 32) ? -1.0f : 1.0f;
    const float sy = sz * sx;

#pragma unroll
    for (int f = 0; f < 48; ++f) {
        const int c = f % 3;                 // compile-time after unroll
        const float sc = (c == 0) ? sz : ((c == 1) ? sy : sx);
        fr[f] = fr[f] * sc;
    }

    float4* __restrict__ o4 = reinterpret_cast<float4*>(rot)
                              + (long long)g * 48 + k * 12;
#pragma unroll
    for (int q = 0; q < 12; ++q) {
        float4 t;
        t.x = fr[4 * q + 0];
        t.y = fr[4 * q + 1];
        t.z = fr[4 * q + 2];
        t.w = fr[4 * q + 3];
        o4[q] = t;
    }

    // lrfs[c][d]: row c = component, col d selects (z,y,x). Lane m (m<3)
    // writes row m: (sz*z0[m], sy*y0[m], sx*x0[m]) — exact +-negation.
    if (k < 3) {
        const float zc = ((k == 0) ? zv0 : ((k == 1) ? zv1 : zv2)) * sz;
        const float yc = ((k == 0) ? yv0 : ((k == 1) ? yv1 : yv2)) * sy;
        const float xc = ((k == 0) ? xv0 : ((k == 1) ? xv1 : xv2)) * sx;
        float* __restrict__ lp = lrf + (long long)g * 9 + 3 * k;
        lp[0] = zc;
        lp[1] = yc;
        lp[2] = xc;
    }
}

extern "C" void kernel_launch(void* const* d_in, const int* in_sizes, int n_in,
                              void* d_out, int out_size, void* d_ws, size_t ws_size,
                              hipStream_t stream) {
    const float* neighbor = (const float*)d_in[0];
    // d_in[1] (center) is unused by the reference computation.
    float* rot = (float*)d_out;                                  // (B,G,S,3)
    float* lrf = (float*)d_out + (long long)64 * 2048 * 64 * 3;  // (B,G,3,3)

    lrf_kernel<<<dim3(2048), dim3(256), 0, stream>>>(neighbor, rot, lrf);
}

// Round 4
// 272.406 us; speedup vs baseline: 3.5761x; 1.0089x over previous
//
#include <hip/hip_runtime.h>
#include <math.h>

// B=64, G=2048, S=64, C=3 -> 131072 groups.
// Hybrid decomposition, bit-faithful LAPACK ssyevd emulation:
//  - memory-touching / lane-parallel phases (norms, ws, wq, cov, flip counts,
//    rot) run on 4-lane clusters (256 thr = 64 groups/block) for occupancy;
//  - the register-only eigen solve (ssytd2+ssteqr+sormtr) runs lane-per-group
//    on wave 0 only (64 groups/wave), amortizing its VALU issue 4x vs R2.
// LDS handoff: cov6 (6 entries/group) in, unflipped z/x axes out (reusing the
// dead wq region). Outputs bit-identical to previous rounds.

__device__ __forceinline__ float slapy2_(float x, float y) {
    _Pragma("clang fp contract(off)")
    float xa = fabsf(x), ya = fabsf(y);
    float w = fmaxf(xa, ya), z = fminf(xa, ya);
    if (z == 0.0f) return w;
    float t = z / w;
    return w * sqrtf(1.0f + t * t);
}

// LAPACK >= 3.10 slartg (fast path; magnitudes mid-range).
__device__ __forceinline__ void slartg_(float f, float g,
                                        float &c, float &s, float &r) {
    _Pragma("clang fp contract(off)")
    if (g == 0.0f) { c = 1.0f; s = 0.0f; r = f; return; }
    if (f == 0.0f) { c = 0.0f; s = (g >= 0.0f) ? 1.0f : -1.0f; r = fabsf(g); return; }
    float d = sqrtf(f * f + g * g);
    float p = 1.0f / d;
    c = fabsf(f) * p;
    s = g * ((f >= 0.0f) ? p : -p);
    r = (f >= 0.0f) ? d : -d;
}

__device__ __forceinline__ void slaev2_(float a, float b, float cc,
                                        float &rt1, float &rt2,
                                        float &cs1, float &sn1) {
    _Pragma("clang fp contract(off)")
    float sm = a + cc, df = a - cc;
    float adf = fabsf(df);
    float tb = b + b;
    float ab = fabsf(tb);
    float acmx, acmn;
    if (fabsf(a) > fabsf(cc)) { acmx = a; acmn = cc; } else { acmx = cc; acmn = a; }
    float rt;
    if (adf > ab)      { float t = ab / adf; rt = adf * sqrtf(1.0f + t * t); }
    else if (adf < ab) { float t = adf / ab; rt = ab * sqrtf(1.0f + t * t); }
    else                rt = ab * sqrtf(2.0f);
    int sgn1;
    if (sm < 0.0f)      { rt1 = 0.5f * (sm - rt); sgn1 = -1; rt2 = (acmx / rt1) * acmn - (b / rt1) * b; }
    else if (sm > 0.0f) { rt1 = 0.5f * (sm + rt); sgn1 =  1; rt2 = (acmx / rt1) * acmn - (b / rt1) * b; }
    else                { rt1 = 0.5f * rt; rt2 = -0.5f * rt; sgn1 = 1; }
    int sgn2;
    float cs;
    if (df >= 0.0f) { cs = df + rt; sgn2 = 1; } else { cs = df - rt; sgn2 = -1; }
    float acs = fabsf(cs);
    if (acs > ab) {
        float ct = -tb / cs;
        sn1 = 1.0f / sqrtf(1.0f + ct * ct);
        cs1 = ct * sn1;
    } else {
        if (ab == 0.0f) { cs1 = 1.0f; sn1 = 0.0f; }
        else {
            float tn = -cs / tb;
            cs1 = 1.0f / sqrtf(1.0f + tn * tn);
            sn1 = tn * cs1;
        }
    }
    if (sgn1 == sgn2) { float tn = cs1; cs1 = -sn1; sn1 = tn; }
}

// --- register-resident accessors for 1-based d[1..3], e[1..2] (cndmask, no scratch) ---
__device__ __forceinline__ float getd3(int i, float d1, float d2, float d3) {
    return (i == 1) ? d1 : ((i == 2) ? d2 : d3);
}
__device__ __forceinline__ void setd3(int i, float v, float &d1, float &d2, float &d3) {
    d1 = (i == 1) ? v : d1;
    d2 = (i == 2) ? v : d2;
    d3 = (i == 3) ? v : d3;
}
__device__ __forceinline__ float gete2(int i, float e1, float e2) {
    return (i == 1) ? e1 : e2;
}
__device__ __forceinline__ void sete2(int i, float v, float &e1, float &e2) {
    e1 = (i == 1) ? v : e1;
    e2 = (i == 2) ? v : e2;
}

// slasr single rotation on columns (j, j+1), j in {1,2}; exact reference formula.
__device__ __forceinline__ void zrot3r(int j, float ctemp, float stemp,
                                       float &z11, float &z12, float &z13,
                                       float &z21, float &z22, float &z23,
                                       float &z31, float &z32, float &z33) {
    _Pragma("clang fp contract(off)")
    if (j == 1) {
        { float t = z12; z12 = (ctemp * t) - (stemp * z11); z11 = (stemp * t) + (ctemp * z11); }
        { float t = z22; z22 = (ctemp * t) - (stemp * z21); z21 = (stemp * t) + (ctemp * z21); }
        { float t = z32; z32 = (ctemp * t) - (stemp * z31); z31 = (stemp * t) + (ctemp * z31); }
    } else {
        { float t = z13; z13 = (ctemp * t) - (stemp * z12); z12 = (stemp * t) + (ctemp * z12); }
        { float t = z23; z23 = (ctemp * t) - (stemp * z22); z22 = (stemp * t) + (ctemp * z22); }
        { float t = z33; z33 = (ctemp * t) - (stemp * z32); z32 = (stemp * t) + (ctemp * z32); }
    }
}

// ssteqr('I') n=3, faithful LAPACK control flow, all state in registers.
__device__ __forceinline__ void ssteqr3_reg(
        float &d1_, float &d2_, float &d3_, float &e1_, float &e2_,
        float &z11, float &z12, float &z13,
        float &z21, float &z22, float &z23,
        float &z31, float &z32, float &z33) {
    _Pragma("clang fp contract(off)")
    const float EPS    = 5.9604644775390625e-8f;   // slamch('E') = 2^-24
    const float EPS2   = EPS * EPS;
    const float SAFMIN = 1.17549435e-38f;
    const int n = 3, nmaxit = 3 * 30;
    int jtot = 0, l1 = 1;

#define GD(i)      getd3((i), d1_, d2_, d3_)
#define SD(i, v)   setd3((i), (v), d1_, d2_, d3_)
#define GE(i)      gete2((i), e1_, e2_)
#define SE(i, v)   sete2((i), (v), e1_, e2_)
#define ZR(j, c, s) zrot3r((j), (c), (s), z11, z12, z13, z21, z22, z23, z31, z32, z33)

    while (true) {                       // label 10
        if (l1 > n) break;
        if (l1 > 1) SE(l1 - 1, 0.0f);
        int m = n;
        for (int mm = l1; mm <= n - 1; ++mm) {
            float tst = fabsf(GE(mm));
            if (tst == 0.0f) { m = mm; break; }
            if (tst <= (sqrtf(fabsf(GD(mm))) * sqrtf(fabsf(GD(mm + 1)))) * EPS) {
                SE(mm, 0.0f); m = mm; break;
            }
        }
        int l = l1, lsv = l, lend = m, lendsv = lend;
        l1 = m + 1;
        if (lend == l) continue;
        // slascl scaling skipped: block norms ~1e2..1e4, inside [ssfmin, ssfmax]
        if (fabsf(GD(lend)) < fabsf(GD(l))) { lend = lsv; l = lendsv; }

        if (lend > l) {
            // ---- QL ----
            while (true) {               // label 40
                m = lend;
                if (l != lend) {
                    for (int mm = l; mm <= lend - 1; ++mm) {
                        float em = GE(mm);
                        float tst = em * em;
                        if (tst <= (EPS2 * fabsf(GD(mm))) * fabsf(GD(mm + 1)) + SAFMIN) { m = mm; break; }
                    }
                }
                if (m < lend) SE(m, 0.0f);
                float p = GD(l);
                if (m == l) {            // label 80
                    SD(l, p); ++l;
                    if (l <= lend) continue;
                    break;
                }
                if (m == l + 1) {
                    float rt1, rt2, c, s;
                    slaev2_(GD(l), GE(l), GD(l + 1), rt1, rt2, c, s);
                    ZR(l, c, s);
                    SD(l, rt1); SD(l + 1, rt2); SE(l, 0.0f);
                    l += 2;
                    if (l <= lend) continue;
                    break;
                }
                if (jtot == nmaxit) break;
                ++jtot;
                {
                    float el = GE(l);
                    float g = (GD(l + 1) - p) / (2.0f * el);
                    float r = slapy2_(g, 1.0f);
                    g = GD(m) - p + el / (g + ((g >= 0.0f) ? r : -r));  // sign(r,g)
                    float s = 1.0f, c = 1.0f;
                    p = 0.0f;
                    for (int i = m - 1; i >= l; --i) {
                        float ei = GE(i);
                        float f = s * ei;
                        float b = c * ei;
                        slartg_(g, f, c, s, r);
                        if (i != m - 1) SE(i + 1, r);
                        g = GD(i + 1) - p;
                        float r2 = ((GD(i) - g) * s) + ((2.0f * c) * b);
                        p = s * r2;
                        SD(i + 1, g + p);
                        g = (c * r2) - b;
                        ZR(i, c, -s);    // QL stores -s
                    }
                    SD(l, GD(l) - p);
                    SE(l, g);
                }
            }
        } else if (lend < l) {
            // ---- QR ----
            while (true) {               // label 90
                m = lend;
                if (l != lend) {
                    for (int mm = l; mm >= lend + 1; --mm) {
                        float em = GE(mm - 1);
                        float tst = em * em;
                        if (tst <= (EPS2 * fabsf(GD(mm))) * fabsf(GD(mm - 1)) + SAFMIN) { m = mm; break; }
                    }
                }
                if (m > lend) SE(m - 1, 0.0f);
                float p = GD(l);
                if (m == l) {            // label 130
                    SD(l, p); --l;
                    if (l >= lend) continue;
                    break;
                }
                if (m == l - 1) {
                    float rt1, rt2, c, s;
                    slaev2_(GD(l - 1), GE(l - 1), GD(l), rt1, rt2, c, s);
                    ZR(l - 1, c, s);
                    SD(l - 1, rt1); SD(l, rt2); SE(l - 1, 0.0f);
                    l -= 2;
                    if (l >= lend) continue;
                    break;
                }
                if (jtot == nmaxit) break;
                ++jtot;
                {
                    float el = GE(l - 1);
                    float g = (GD(l - 1) - p) / (2.0f * el);
                    float r = slapy2_(g, 1.0f);
                    g = GD(m) - p + el / (g + ((g >= 0.0f) ? r : -r));
                    float s = 1.0f, c = 1.0f;
                    p = 0.0f;
                    for (int i = m; i <= l - 1; ++i) {
                        float ei = GE(i);
                        float f = s * ei;
                        float b = c * ei;
                        slartg_(g, f, c, s, r);
                        if (i != m) SE(i - 1, r);
                        g = GD(i) - p;
                        float r2 = ((GD(i + 1) - g) * s) + ((2.0f * c) * b);
                        p = s * r2;
                        SD(i, g + p);
                        g = (c * r2) - b;
                        ZR(i, c, s);     // QR stores +s
                    }
                    SD(l, GD(l) - p);
                    SE(l - 1, g);
                }
            }
        }
    }
    // label 160: selection sort ascending + eigenvector column swaps (n=3).
    {
        int k = 1; float p = d1_;
        if (d2_ < p) { k = 2; p = d2_; }
        if (d3_ < p) { k = 3; p = d3_; }
        if (k == 2) {
            d2_ = d1_; d1_ = p;
            float t;
            t = z11; z11 = z12; z12 = t;
            t = z21; z21 = z22; z22 = t;
            t = z31; z31 = z32; z32 = t;
        } else if (k == 3) {
            d3_ = d1_; d1_ = p;
            float t;
            t = z11; z11 = z13; z13 = t;
            t = z21; z21 = z23; z23 = t;
            t = z31; z31 = z33; z33 = t;
        }
        if (d3_ < d2_) {
            float t = d2_; d2_ = d3_; d3_ = t;
            t = z12; z12 = z13; z13 = t;
            t = z22; z22 = z23; z23 = t;
            t = z32; z32 = z33; z33 = t;
        }
    }
#undef GD
#undef SD
#undef GE
#undef SE
#undef ZR
}

__device__ __forceinline__ float nrm3_(float x, float y, float z) {
    _Pragma("clang fp contract(off)")
    float t = (x * x) + (y * y);    // np order ((x*x + y*y) + z*z), no FMA
    t = t + (z * z);
    return sqrtf(t);
}

// cov accumulation step; wq precomputed as (mx - nrm)/denom (identical value).
__device__ __forceinline__ void covstep(float px, float py, float pz, float wq,
                                        float &c00, float &c10, float &c20,
                                        float &c11, float &c21, float &c22) {
    _Pragma("clang fp contract(off)")
    const float spx = 100.0f * px, spy = 100.0f * py, spz = 100.0f * pz;
    const float ax = wq * spx, ay = wq * spy, az = wq * spz;
    c00 = c00 + (ax * spx);
    c10 = c10 + (ay * spx);
    c20 = c20 + (az * spx);
    c11 = c11 + (ay * spy);
    c21 = c21 + (az * spy);
    c22 = c22 + (az * spz);
}

// flip-count step: z-dot and x-dot only (reference order), exact comparisons.
__device__ __forceinline__ void projstep(float px, float py, float pz,
                                         float zv0, float zv1, float zv2,
                                         float xv0, float xv1, float xv2,
                                         int &cz, int &cx) {
    _Pragma("clang fp contract(off)")
    const float pjz = ((zv0 * px) + (zv1 * py)) + (zv2 * pz);
    const float pjx = ((xv0 * px) + (xv1 * py)) + (xv2 * pz);
    cz += (pjz > 0.0f) ? 1 : 0;
    cx += (pjx > 0.0f) ? 1 : 0;
}

// rot row: dots with UNFLIPPED axes, then exact +-1 scale (distributes exactly).
__device__ __forceinline__ void rotstep(float px, float py, float pz,
                                        float zv0, float zv1, float zv2,
                                        float yv0, float yv1, float yv2,
                                        float xv0, float xv1, float xv2,
                                        float sz, float sy, float sx,
                                        float &ra, float &rb, float &rc) {
    _Pragma("clang fp contract(off)")
    ra = (((px * zv0) + (py * zv1)) + (pz * zv2)) * sz;
    rb = (((px * yv0) + (py * yv1)) + (pz * yv2)) * sy;
    rc = (((px * xv0) + (py * xv1)) + (pz * xv2)) * sx;
}

__global__ __launch_bounds__(256, 4) void lrf_kernel(const float* __restrict__ nbr,
                                                     float* __restrict__ rot,
                                                     float* __restrict__ lrf) {
    _Pragma("clang fp contract(off)")
    // 256 threads = 64 groups/block, 4-lane cluster per group.
    // wql: norms -> wq (stride 65, conflict-free); region [0,448) reused for
    // unflipped axes after the eigen phase. cov6: 6 cov entries/group, stride 7.
    __shared__ float wql[64 * 65];
    __shared__ float cov6[64 * 7];
    const int tid = threadIdx.x;
    const int gl  = tid >> 2;               // group-local 0..63
    const int k   = tid & 3;                // cluster lane 0..3
    const int g   = (blockIdx.x << 6) + gl; // global group id
    const int lbase = gl * 65;

    const float4* __restrict__ p4 = reinterpret_cast<const float4*>(nbr)
                                    + (long long)g * 48 + k * 12;   // own 16 samples
    const float4* __restrict__ q4 = reinterpret_cast<const float4*>(nbr)
                                    + (long long)g * 48;            // full group

    // ---- pass 1: own 16 norms -> LDS; cluster max (order-free exact) ----
    float mx = -3.402823466e+38f;
#pragma unroll
    for (int q = 0; q < 4; ++q) {
        const float4 v0 = p4[q * 3 + 0];
        const float4 v1 = p4[q * 3 + 1];
        const float4 v2 = p4[q * 3 + 2];
        const float n0 = nrm3_(v0.x, v0.y, v0.z);
        const float n1 = nrm3_(v0.w, v1.x, v1.y);
        const float n2 = nrm3_(v1.z, v1.w, v2.x);
        const float n3 = nrm3_(v2.y, v2.z, v2.w);
        const int b = lbase + 16 * k + 4 * q;
        wql[b + 0] = n0;
        wql[b + 1] = n1;
        wql[b + 2] = n2;
        wql[b + 3] = n3;
        mx = fmaxf(mx, fmaxf(fmaxf(n0, n1), fmaxf(n2, n3)));
    }
    mx = fmaxf(mx, __shfl_xor(mx, 1, 64));
    mx = fmaxf(mx, __shfl_xor(mx, 2, 64));
    __builtin_amdgcn_wave_barrier();
    asm volatile("" ::: "memory");

    // ---- pass 2: exact pairwise weight sum.
    // Reference: q_j = w_j + w_{j+8} + ... (t ascending), ws = ((q0+q1)+(q2+q3))
    // + ((q4+q5)+(q6+q7)). Lane k computes q_{2k}, q_{2k+1}; shfl tree matches
    // the exact pairing (FP add commutative bitwise).
    float r0_ = 0.0f, r1_ = 0.0f;
    {
        const int j0 = lbase + 2 * k;
#pragma unroll
        for (int t = 0; t < 8; ++t) {
            r0_ = r0_ + (mx - wql[j0 + 8 * t + 0]);
            r1_ = r1_ + (mx - wql[j0 + 8 * t + 1]);
        }
    }
    const float A_ = r0_ + r1_;
    const float B_ = A_ + __shfl_xor(A_, 1, 64);
    const float ws = B_ + __shfl_xor(B_, 2, 64);
    const float denom = ws + 1e-6f;
    asm volatile("" ::: "memory");

    // ---- pass 2b: overwrite own norm slots with wq = (mx-nrm)/denom ----
#pragma unroll
    for (int i = 0; i < 16; ++i) {
        const int idx = lbase + 16 * k + i;
        const float nv = wql[idx];
        wql[idx] = (mx - nv) / denom;
    }
    __builtin_amdgcn_wave_barrier();
    asm volatile("" ::: "memory");

    // ---- pass 3: covariance, strict sequential s=0..63 (redundant on the 4
    // cluster lanes -- free issue-wise within the wave; broadcast loads). ----
    float c00 = 0.0f, c10 = 0.0f, c20 = 0.0f, c11 = 0.0f, c21 = 0.0f, c22 = 0.0f;
#pragma unroll 4
    for (int q = 0; q < 16; ++q) {
        const float4 v0 = q4[q * 3 + 0];
        const float4 v1 = q4[q * 3 + 1];
        const float4 v2 = q4[q * 3 + 2];
        const float w0 = wql[lbase + 4 * q + 0];
        const float w1 = wql[lbase + 4 * q + 1];
        const float w2 = wql[lbase + 4 * q + 2];
        const float w3 = wql[lbase + 4 * q + 3];
        covstep(v0.x, v0.y, v0.z, w0, c00, c10, c20, c11, c21, c22);
        covstep(v0.w, v1.x, v1.y, w1, c00, c10, c20, c11, c21, c22);
        covstep(v1.z, v1.w, v2.x, w2, c00, c10, c20, c11, c21, c22);
        covstep(v2.y, v2.z, v2.w, w3, c00, c10, c20, c11, c21, c22);
    }

    // ---- handoff: distribute the 6 cov entries across cluster lanes ----
    // layout: cov6[gl*7 + {0:a11,1:a21,2:a31,3:a22,4:a32,5:a33}]
    {
        const float vA = (k == 0) ? c00 : ((k == 1) ? c10 : ((k == 2) ? c20 : c11));
        cov6[gl * 7 + k] = vA;
        if (k < 2) {
            const float vB = (k == 0) ? c21 : c22;
            cov6[gl * 7 + 4 + k] = vB;
        }
    }
    __syncthreads();   // barrier 1: cov6 complete; wql (wq) dead after this

    // ---- eigen phase: wave 0 only, lane-per-group (64 groups) ----
    if (tid < 64) {
        const int tb = tid * 7;
        const float a11 = cov6[tb + 0];
        const float a21 = cov6[tb + 1];
        const float a31 = cov6[tb + 2];
        const float a22 = cov6[tb + 3];
        const float a32 = cov6[tb + 4];
        const float a33 = cov6[tb + 5];

        // --- ssytd2 (UPLO='L', n=3), exact reference-BLAS op order ---
        float taui, v2h, e1q, d2q, d3q, e2q;
        const float xnorm = fabsf(a31);   // snrm2(1,x)
        if (xnorm == 0.0f) {
            taui = 0.0f; v2h = a31; e1q = a21; d2q = a22; e2q = a32; d3q = a33;
        } else {
            const float beta = -copysignf(slapy2_(a21, xnorm), a21);
            taui = (beta - a21) / beta;
            const float rcp = 1.0f / (a21 - beta);   // sscal multiplies by reciprocal
            v2h = a31 * rcp;
            e1q = beta;
            // ssymv (reference order), alpha=taui, x=(1,v2), y:=0:
            float x1 = taui * a22;
            float x2 = taui * a32;
            const float temp2 = a32 * v2h;
            x1 = x1 + (taui * temp2);
            const float t1v = taui * v2h;
            x2 = x2 + (t1v * a33);
            const float dt = x1 + (x2 * v2h);        // sdot sequential
            const float alpha_c = (-0.5f * taui) * dt;
            const float w1 = x1 + alpha_c;           // saxpy
            const float w2 = x2 + (alpha_c * v2h);
            d2q = (a22 - w1) - w1;                   // ssyr2 alpha=-1, reference order
            e2q = (a32 - (v2h * w1)) - w2;
            d3q = (a33 - (v2h * w2)) - (w2 * v2h);
        }

        float d1_ = a11, d2_ = d2q, d3_ = d3q, e1_ = e1q, e2_ = e2q;
        float z11 = 1.0f, z12 = 0.0f, z13 = 0.0f;
        float z21 = 0.0f, z22 = 1.0f, z23 = 0.0f;
        float z31 = 0.0f, z32 = 0.0f, z33 = 1.0f;
        ssteqr3_reg(d1_, d2_, d3_, e1_, e2_,
                    z11, z12, z13, z21, z22, z23, z31, z32, z33);

        // --- sormtr/sorm2r/slarf: apply H = I - tau*v*v' to columns 1 and 3 ---
        float zv0, zv1, zv2, xv0, xv1, xv2;
        {
            const float u2 = z21, u3 = z31;
            zv0 = z11;
            if (taui != 0.0f) {
                const float wj = u2 + (u3 * v2h);   // sgemv 'T'
                const float pj = taui * wj;         // sger
                zv1 = u2 - pj;
                zv2 = u3 - (v2h * pj);
            } else { zv1 = u2; zv2 = u3; }
        }
        {
            const float u2 = z23, u3 = z33;
            xv0 = z13;
            if (taui != 0.0f) {
                const float wj = u2 + (u3 * v2h);
                const float pj = taui * wj;
                xv1 = u2 - pj;
                xv2 = u3 - (v2h * pj);
            } else { xv1 = u2; xv2 = u3; }
        }

        // write unflipped axes into the dead wq region (stride 7, conflict-free)
        wql[tb + 0] = zv0;
        wql[tb + 1] = zv1;
        wql[tb + 2] = zv2;
        wql[tb + 3] = xv0;
        wql[tb + 4] = xv1;
        wql[tb + 5] = xv2;
    }
    __syncthreads();   // barrier 2: axes visible to all waves

    // ---- read axes (cluster-broadcast), recompute cross (exact, redundant) ----
    const int ab = gl * 7;
    const float zv0 = wql[ab + 0], zv1 = wql[ab + 1], zv2 = wql[ab + 2];
    const float xv0 = wql[ab + 3], xv1 = wql[ab + 4], xv2 = wql[ab + 5];

    // y0 = cross(z0, x0) unflipped; final y = (sz*sx)*y0 is bitwise equal to
    // the reference's cross of flipped axes (sign flips are exact in *, -).
    const float yv0 = (zv1 * xv2) - (zv2 * xv1);
    const float yv1 = (zv2 * xv0) - (zv0 * xv2);
    const float yv2 = (zv0 * xv1) - (zv1 * xv0);

    // ---- pass 4: sign counts over own 16 samples, cluster-reduce ----
    int cz = 0, cx = 0;
#pragma unroll
    for (int q = 0; q < 4; ++q) {
        const float4 v0 = p4[q * 3 + 0];
        const float4 v1 = p4[q * 3 + 1];
        const float4 v2 = p4[q * 3 + 2];
        projstep(v0.x, v0.y, v0.z, zv0, zv1, zv2, xv0, xv1, xv2, cz, cx);
        projstep(v0.w, v1.x, v1.y, zv0, zv1, zv2, xv0, xv1, xv2, cz, cx);
        projstep(v1.z, v1.w, v2.x, zv0, zv1, zv2, xv0, xv1, xv2, cz, cx);
        projstep(v2.y, v2.z, v2.w, zv0, zv1, zv2, xv0, xv1, xv2, cz, cx);
    }
    cz += __shfl_xor(cz, 1, 64);
    cz += __shfl_xor(cz, 2, 64);
    cx += __shfl_xor(cx, 1, 64);
    cx += __shfl_xor(cx, 2, 64);
    const float sz = (cz < 32) ? -1.0f : 1.0f;
    const float sx = (cx < 32) ? -1.0f : 1.0f;
    const float sy = sz * sx;

    // ---- pass 5: rot rows (re-read own samples; L2-warm), coalesced store ----
    float4* __restrict__ o4 = reinterpret_cast<float4*>(rot)
                              + (long long)g * 48 + k * 12;
#pragma unroll
    for (int q = 0; q < 4; ++q) {
        const float4 v0 = p4[q * 3 + 0];
        const float4 v1 = p4[q * 3 + 1];
        const float4 v2 = p4[q * 3 + 2];
        float r0a, r0b, r0c, r1a, r1b, r1c, r2a, r2b, r2c, r3a, r3b, r3c;
        rotstep(v0.x, v0.y, v0.z, zv0, zv1, zv2, yv0, yv1, yv2, xv0, xv1, xv2,
                sz, sy, sx, r0a, r0b, r0c);
        rotstep(v0.w, v1.x, v1.y, zv0, zv1, zv2, yv0, yv1, yv2, xv0, xv1, xv2,
                sz, sy, sx, r1a, r1b, r1c);
        rotstep(v1.z, v1.w, v2.x, zv0, zv1, zv2, yv0, yv1, yv2, xv0, xv1, xv2,
                sz, sy, sx, r2a, r2b, r2c);
        rotstep(v2.y, v2.z, v2.w, zv0, zv1, zv2, yv0, yv1, yv2, xv0, xv1, xv2,
                sz, sy, sx, r3a, r3b, r3c);
        float4 o0, o1, o2;
        o0.x = r0a; o0.y = r0b; o0.z = r0c; o0.w = r1a;
        o1.x = r1b; o1.y = r1c; o1.z = r2a; o1.w = r2b;
        o2.x = r2c; o2.y = r3a; o2.z = r3b; o2.w = r3c;
        o4[q * 3 + 0] = o0;
        o4[q * 3 + 1] = o1;
        o4[q * 3 + 2] = o2;
    }

    // lrfs[c][d]: row c = component, col d selects (z,y,x). Lane m (m<3)
    // writes row m: (sz*z0[m], sy*y0[m], sx*x0[m]) -- exact +-negation.
    if (k < 3) {
        const float zc = ((k == 0) ? zv0 : ((k == 1) ? zv1 : zv2)) * sz;
        const float yc = ((k == 0) ? yv0 : ((k == 1) ? yv1 : yv2)) * sy;
        const float xc = ((k == 0) ? xv0 : ((k == 1) ? xv1 : xv2)) * sx;
        float* __restrict__ lp = lrf + (long long)g * 9 + 3 * k;
        lp[0] = zc;
        lp[1] = yc;
        lp[2] = xc;
    }
}

extern "C" void kernel_launch(void* const* d_in, const int* in_sizes, int n_in,
                              void* d_out, int out_size, void* d_ws, size_t ws_size,
                              hipStream_t stream) {
    const float* neighbor = (const float*)d_in[0];
    // d_in[1] (center) is unused by the reference computation.
    float* rot = (float*)d_out;                                  // (B,G,S,3)
    float* lrf = (float*)d_out + (long long)64 * 2048 * 64 * 3;  // (B,G,3,3)

    lrf_kernel<<<dim3(2048), dim3(256), 0, stream>>>(neighbor, rot, lrf);
}